// Round 4
// baseline (670.863 us; speedup 1.0000x reference)
//
#include <hip/hip_runtime.h>

#define SEQ 550
#define MID 100

typedef _Float16 half2_t __attribute__((ext_vector_type(2)));
typedef __fp16   pkh2_t  __attribute__((ext_vector_type(2)));   // cvt_pkrtz return type
union H2I  { int i; half2_t h; ushort2 u2; };
union PK2I { int i; pkh2_t  p; };

__device__ __forceinline__ float fdot2(half2_t a, half2_t b, float c) {
    return __builtin_amdgcn_fdot2(a, b, c, false);
}
__device__ __forceinline__ float sigm(float x)  { return 1.0f / (1.0f + __expf(-x)); }
__device__ __forceinline__ float tanh_f(float x){ return 1.0f - 2.0f / (__expf(2.0f * x) + 1.0f); }
__device__ __forceinline__ half2_t i2h(int v)   { H2I u; u.i = v; return u.h; }
__device__ __forceinline__ int pk2i(float lo, float hi) {
    PK2I u; u.p = __builtin_amdgcn_cvt_pkrtz(lo, hi); return u.i;
}

__global__ __launch_bounds__(64, 1) void gru_wave(
    const int*   __restrict__ x,
    const float* __restrict__ hidden,
    const float* __restrict__ embed,
    const float* __restrict__ w_ih,
    const float* __restrict__ w_hh,
    const float* __restrict__ b_ih,
    const float* __restrict__ b_hh,
    const float* __restrict__ fc_w,
    const float* __restrict__ fc_b,
    float*       __restrict__ out)
{
    __shared__ __align__(16) ushort seq16[SEQ * 16];   // emb fp16, 32B/t
    __shared__ float gates[MID * 5];                   // [unit][r, z, gi_n, gh_n, pad]
    __shared__ float partial[64];

    const int lane = threadIdx.x;

    // ---- stage embedded sequence as fp16 (once) ----
    for (int t = lane; t < SEQ; t += 64) {
        int idx = x[t];
        const float2* er = (const float2*)(embed + idx * 10);  // 40B rows: 8B aligned
        float2 e0 = er[0], e1 = er[1], e2 = er[2], e3 = er[3], e4 = er[4];
        int* d = (int*)&seq16[t * 16];
        d[0] = pk2i(e0.x, e0.y);
        d[1] = pk2i(e1.x, e1.y);
        d[2] = pk2i(e2.x, e2.y);
        d[3] = pk2i(e3.x, e3.y);
        d[4] = pk2i(e4.x, e4.y);
    }

    // ---- per-lane weights: rows {lane + 60*r}, lanes 0..59 ----
    half2_t whh[5][50];
    half2_t wih[5][5];
    float   bih[5], bhh[5];
    if (lane < 60) {
        #pragma unroll
        for (int r = 0; r < 5; r++) {
            const int m = lane + 60 * r;
            const float4* wr = (const float4*)(w_hh + m * MID);  // 400B: 16B aligned
            #pragma unroll
            for (int k = 0; k < 25; k++) {
                float4 f = wr[k];
                whh[r][2 * k]     = half2_t{(_Float16)f.x, (_Float16)f.y};
                whh[r][2 * k + 1] = half2_t{(_Float16)f.z, (_Float16)f.w};
            }
            const float2* wi = (const float2*)(w_ih + m * 10);
            #pragma unroll
            for (int k = 0; k < 5; k++) {
                float2 f = wi[k];
                wih[r][k] = half2_t{(_Float16)f.x, (_Float16)f.y};
            }
            bih[r] = b_ih[m];
            bhh[r] = b_hh[m];
        }
    }

    // ---- h state: lane l<50 owns units 2l, 2l+1 (fp32), packed fp16 in hpk ----
    float hreg0 = 0.0f, hreg1 = 0.0f;
    int   hpk   = 0;
    if (lane < 50) {
        hreg0 = hidden[2 * lane];
        hreg1 = hidden[2 * lane + 1];
        hpk = pk2i(hreg0, hreg1);
    }

    __syncthreads();   // emb staging visible to all lanes

    #pragma unroll 1
    for (int t = 0; t < SEQ; t++) {
        // ---- h broadcast: pure register traffic, no LDS ----
        int hs[50];
        #pragma unroll
        for (int k = 0; k < 50; k++) hs[k] = __builtin_amdgcn_readlane(hpk, k);

        // ---- emb_t broadcast (same-address LDS reads) ----
        const int* eb = (const int*)&seq16[t * 16];   // 32B aligned
        int4 e4 = *(const int4*)eb;
        int  ew = eb[4];
        half2_t e[5] = {i2h(e4.x), i2h(e4.y), i2h(e4.z), i2h(e4.w), i2h(ew)};

        // ---- 5 gate-projection rows per lane ----
        if (lane < 60) {
            #pragma unroll
            for (int r = 0; r < 5; r++) {
                float a0 = bhh[r], a1 = 0.0f, a2 = 0.0f, a3 = 0.0f;
                #pragma unroll
                for (int k = 0; k < 48; k += 4) {
                    a0 = fdot2(whh[r][k],     i2h(hs[k]),     a0);
                    a1 = fdot2(whh[r][k + 1], i2h(hs[k + 1]), a1);
                    a2 = fdot2(whh[r][k + 2], i2h(hs[k + 2]), a2);
                    a3 = fdot2(whh[r][k + 3], i2h(hs[k + 3]), a3);
                }
                a0 = fdot2(whh[r][48], i2h(hs[48]), a0);
                a1 = fdot2(whh[r][49], i2h(hs[49]), a1);
                float gh = (a0 + a1) + (a2 + a3);

                float gi = bih[r];
                #pragma unroll
                for (int k = 0; k < 5; k++) gi = fdot2(wih[r][k], e[k], gi);

                const int m = lane + 60 * r;
                if (m < 100)      gates[m * 5 + 0] = gi + gh;
                else if (m < 200) gates[(m - 100) * 5 + 1] = gi + gh;
                else { gates[(m - 200) * 5 + 2] = gi; gates[(m - 200) * 5 + 3] = gh; }
            }
        }
        __syncthreads();   // single wave: compiles to lgkm fence, cheap

        // ---- gate mixing + h update: lanes 0..49, 2 units each ----
        if (lane < 50) {
            const float* gp = &gates[lane * 10];
            float r0 = sigm(gp[0]), z0 = sigm(gp[1]);
            float n0 = tanh_f(gp[2] + r0 * gp[3]);
            hreg0 = n0 + z0 * (hreg0 - n0);
            float r1 = sigm(gp[5]), z1 = sigm(gp[6]);
            float n1 = tanh_f(gp[7] + r1 * gp[8]);
            hreg1 = n1 + z1 * (hreg1 - n1);
            hpk = pk2i(hreg0, hreg1);
        }
        __syncthreads();   // order gate reads vs next iter's writes
    }

    // ---- epilogue: sigmoid(relu(h) . fc_w + fc_b) ----
    if (lane < 50)
        partial[lane] = fmaxf(hreg0, 0.0f) * fc_w[2 * lane]
                      + fmaxf(hreg1, 0.0f) * fc_w[2 * lane + 1];
    else
        partial[lane] = 0.0f;
    __syncthreads();
    if (lane == 0) {
        float s = fc_b[0];
        #pragma unroll 1
        for (int k = 0; k < 50; k++) s += partial[k];
        out[0] = sigm(s);
    }
}

extern "C" void kernel_launch(void* const* d_in, const int* in_sizes, int n_in,
                              void* d_out, int out_size, void* d_ws, size_t ws_size,
                              hipStream_t stream) {
    const int*   x      = (const int*)  d_in[0];
    const float* hidden = (const float*)d_in[1];
    const float* embed  = (const float*)d_in[2];
    const float* w_ih   = (const float*)d_in[3];
    const float* w_hh   = (const float*)d_in[4];
    const float* b_ih   = (const float*)d_in[5];
    const float* b_hh   = (const float*)d_in[6];
    const float* fc_w   = (const float*)d_in[7];
    const float* fc_b   = (const float*)d_in[8];
    float*       out    = (float*)d_out;

    gru_wave<<<1, 64, 0, stream>>>(x, hidden, embed, w_ih, w_hh,
                                   b_ih, b_hh, fc_w, fc_b, out);
}

// Round 5
// 583.511 us; speedup vs baseline: 1.1497x; 1.1497x over previous
//
#include <hip/hip_runtime.h>

#define SEQ 550
#define MID 100
#define TPB 320
#define GST 104   // gate array stride (units), 104*4B keeps b64 alignment

typedef _Float16 half2_t __attribute__((ext_vector_type(2)));
typedef __fp16   pkh2_t  __attribute__((ext_vector_type(2)));   // cvt_pkrtz return type
union H2I  { int i; half2_t h; };
union PK2I { int i; pkh2_t  p; };

__device__ __forceinline__ float fdot2(half2_t a, half2_t b, float c) {
    return __builtin_amdgcn_fdot2(a, b, c, false);
}
__device__ __forceinline__ float sigm(float x)  { return 1.0f / (1.0f + __expf(-x)); }
__device__ __forceinline__ float tanh_f(float x){ return 1.0f - 2.0f / (__expf(2.0f * x) + 1.0f); }
__device__ __forceinline__ half2_t i2h(int v)   { H2I u; u.i = v; return u.h; }
__device__ __forceinline__ int pk2i(float lo, float hi) {
    PK2I u; u.p = __builtin_amdgcn_cvt_pkrtz(lo, hi); return u.i;
}

__global__ __launch_bounds__(TPB, 1) void gru5w(
    const int*   __restrict__ x,
    const float* __restrict__ hidden,
    const float* __restrict__ embed,
    const float* __restrict__ w_ih,
    const float* __restrict__ w_hh,
    const float* __restrict__ b_ih,
    const float* __restrict__ b_hh,
    const float* __restrict__ fc_w,
    const float* __restrict__ fc_b,
    float*       __restrict__ out)
{
    __shared__ __align__(16) ushort seq16[SEQ * 16];     // emb fp16, 32B/t
    __shared__ __align__(16) float gates[2][4][GST];     // double-buffered [buf][gate][unit]
    __shared__ float partial[64];

    const int tid  = threadIdx.x;
    const int lane = tid & 63;

    // ---- stage embedded sequence as fp16 (once) ----
    for (int t = tid; t < SEQ; t += TPB) {
        int idx = x[t];
        const float2* er = (const float2*)(embed + idx * 10);  // 40B rows, 8B aligned
        float2 e0 = er[0], e1 = er[1], e2 = er[2], e3 = er[3], e4 = er[4];
        int* d = (int*)&seq16[t * 16];
        d[0] = pk2i(e0.x, e0.y);
        d[1] = pk2i(e1.x, e1.y);
        d[2] = pk2i(e2.x, e2.y);
        d[3] = pk2i(e3.x, e3.y);
        d[4] = pk2i(e4.x, e4.y);
    }

    // ---- one gate-row per thread: row m = tid (valid for tid < 300) ----
    const int  m      = tid;
    const bool hasrow = (m < 300);
    half2_t whh[50];
    half2_t wih[5];
    float   bih = 0.0f, bhh = 0.0f;
    int     g = 0, u = 0;
    if (hasrow) {
        const float4* wr = (const float4*)(w_hh + m * MID);   // 400B rows: 16B aligned
        #pragma unroll
        for (int k = 0; k < 25; k++) {
            float4 f = wr[k];
            whh[2 * k]     = half2_t{(_Float16)f.x, (_Float16)f.y};
            whh[2 * k + 1] = half2_t{(_Float16)f.z, (_Float16)f.w};
        }
        const float2* wi = (const float2*)(w_ih + m * 10);
        #pragma unroll
        for (int k = 0; k < 5; k++) {
            float2 f = wi[k];
            wih[k] = half2_t{(_Float16)f.x, (_Float16)f.y};
        }
        bih = b_ih[m];
        bhh = b_hh[m];
        g = m / 100;
        u = m - g * 100;
    }

    // ---- h state: EVERY wave keeps a full copy; lane l<50 owns units 2l,2l+1 ----
    const bool ownh = (lane < 50);
    float h0 = 0.0f, h1 = 0.0f;
    int   hpk = 0;
    if (ownh) {
        h0 = hidden[2 * lane];
        h1 = hidden[2 * lane + 1];
        hpk = pk2i(h0, h1);
    }

    __syncthreads();   // emb staging visible

    #pragma unroll 1
    for (int t = 0; t < SEQ; t++) {
        float* gb = &gates[t & 1][0][0];

        // ---- emb_t broadcast (same-address LDS reads, latency hidden under dots) ----
        const int* eb = (const int*)&seq16[t * 16];
        int4 e4 = *(const int4*)eb;
        int  ew = eb[4];

        // ---- hh-matvec: h broadcast via intra-wave readlane (register-only) ----
        float a0 = bhh, a1 = 0.0f, a2 = 0.0f, a3 = 0.0f;
        #pragma unroll
        for (int k = 0; k < 48; k += 4) {
            int hk0 = __builtin_amdgcn_readlane(hpk, k);
            int hk1 = __builtin_amdgcn_readlane(hpk, k + 1);
            int hk2 = __builtin_amdgcn_readlane(hpk, k + 2);
            int hk3 = __builtin_amdgcn_readlane(hpk, k + 3);
            a0 = fdot2(whh[k],     i2h(hk0), a0);
            a1 = fdot2(whh[k + 1], i2h(hk1), a1);
            a2 = fdot2(whh[k + 2], i2h(hk2), a2);
            a3 = fdot2(whh[k + 3], i2h(hk3), a3);
        }
        {
            int hk0 = __builtin_amdgcn_readlane(hpk, 48);
            int hk1 = __builtin_amdgcn_readlane(hpk, 49);
            a0 = fdot2(whh[48], i2h(hk0), a0);
            a1 = fdot2(whh[49], i2h(hk1), a1);
        }
        float gh = (a0 + a1) + (a2 + a3);

        float gi = bih;
        gi = fdot2(wih[0], i2h(e4.x), gi);
        gi = fdot2(wih[1], i2h(e4.y), gi);
        gi = fdot2(wih[2], i2h(e4.z), gi);
        gi = fdot2(wih[3], i2h(e4.w), gi);
        gi = fdot2(wih[4], i2h(ew),   gi);

        if (hasrow) {
            if (g == 2) { gb[2 * GST + u] = gi; gb[3 * GST + u] = gh; }
            else        { gb[g * GST + u] = gi + gh; }
        }
        __syncthreads();   // the ONLY barrier per step (gates double-buffered)

        // ---- phase 2: every wave redundantly updates all 100 units ----
        if (ownh) {
            float2 grv = *(const float2*)&gb[0 * GST + 2 * lane];
            float2 gzv = *(const float2*)&gb[1 * GST + 2 * lane];
            float2 giv = *(const float2*)&gb[2 * GST + 2 * lane];
            float2 ghv = *(const float2*)&gb[3 * GST + 2 * lane];
            float r0 = sigm(grv.x), z0 = sigm(gzv.x);
            float n0 = tanh_f(giv.x + r0 * ghv.x);
            h0 = n0 + z0 * (h0 - n0);
            float r1 = sigm(grv.y), z1 = sigm(gzv.y);
            float n1 = tanh_f(giv.y + r1 * ghv.y);
            h1 = n1 + z1 * (h1 - n1);
            hpk = pk2i(h0, h1);
        }
    }

    // ---- epilogue: sigmoid(relu(h) . fc_w + fc_b), wave 0's copy ----
    if (tid < 50)
        partial[tid] = fmaxf(h0, 0.0f) * fc_w[2 * tid]
                     + fmaxf(h1, 0.0f) * fc_w[2 * tid + 1];
    __syncthreads();
    if (tid == 0) {
        float s = fc_b[0];
        #pragma unroll 1
        for (int k = 0; k < 50; k++) s += partial[k];
        out[0] = sigm(s);
    }
}

extern "C" void kernel_launch(void* const* d_in, const int* in_sizes, int n_in,
                              void* d_out, int out_size, void* d_ws, size_t ws_size,
                              hipStream_t stream) {
    const int*   x      = (const int*)  d_in[0];
    const float* hidden = (const float*)d_in[1];
    const float* embed  = (const float*)d_in[2];
    const float* w_ih   = (const float*)d_in[3];
    const float* w_hh   = (const float*)d_in[4];
    const float* b_ih   = (const float*)d_in[5];
    const float* b_hh   = (const float*)d_in[6];
    const float* fc_w   = (const float*)d_in[7];
    const float* fc_b   = (const float*)d_in[8];
    float*       out    = (float*)d_out;

    gru5w<<<1, TPB, 0, stream>>>(x, hidden, embed, w_ih, w_hh,
                                 b_ih, b_hh, fc_w, fc_b, out);
}

// Round 6
// 577.543 us; speedup vs baseline: 1.1616x; 1.0103x over previous
//
#include <hip/hip_runtime.h>

#define SEQ 550
#define MID 100
#define TPB 320
#define GST 104   // gate row stride (dwords); keeps b64 alignment, breaks pow2

typedef _Float16 half2_t __attribute__((ext_vector_type(2)));
typedef __fp16   pkh2_t  __attribute__((ext_vector_type(2)));   // cvt_pkrtz return type
typedef int      vi16    __attribute__((ext_vector_type(16)));
union H2I  { int i; half2_t h; };
union PK2I { int i; pkh2_t  p; };

__device__ __forceinline__ float fdot2(half2_t a, half2_t b, float c) {
    return __builtin_amdgcn_fdot2(a, b, c, false);
}
__device__ __forceinline__ float sigm(float x)  { return 1.0f / (1.0f + __expf(-x)); }
__device__ __forceinline__ float tanh_f(float x){ return 1.0f - 2.0f / (__expf(2.0f * x) + 1.0f); }
__device__ __forceinline__ half2_t i2h(int v)   { H2I u; u.i = v; return u.h; }
__device__ __forceinline__ int pk2i(float lo, float hi) {
    PK2I u; u.p = __builtin_amdgcn_cvt_pkrtz(lo, hi); return u.i;
}

// Weight element k (0..49) from named vector registers — k is compile-time
// constant after unroll, so the ternaries fold to a direct VGPR reference.
#define WELT(k) ((k) < 16 ? wA[(k)] : (k) < 32 ? wB[(k)-16] : (k) < 48 ? wC[(k)-32] \
                 : ((k) == 48 ? wD0 : wD1))

__global__ __launch_bounds__(TPB, 1) void gru6(
    const int*   __restrict__ x,
    const float* __restrict__ hidden,
    const float* __restrict__ embed,
    const float* __restrict__ w_ih,
    const float* __restrict__ w_hh,
    const float* __restrict__ b_ih,
    const float* __restrict__ b_hh,
    const float* __restrict__ fc_w,
    const float* __restrict__ fc_b,
    float*       __restrict__ out)
{
    __shared__ __align__(16) ushort seq16[SEQ * 16];   // emb fp16, 32B/t
    __shared__ __align__(16) float gates[2][4][GST];   // [buf][gate: r,z,gi_n,gh_n][unit]
    __shared__ float partial[64];

    const int tid  = threadIdx.x;
    const int lane = tid & 63;
    const int wid  = tid >> 6;

    // ---- stage embedded sequence as fp16 (once) ----
    for (int t = tid; t < SEQ; t += TPB) {
        int idx = x[t];
        const float2* er = (const float2*)(embed + idx * 10);  // 40B rows, 8B aligned
        float2 e0 = er[0], e1 = er[1], e2 = er[2], e3 = er[3], e4 = er[4];
        int* d = (int*)&seq16[t * 16];
        d[0] = pk2i(e0.x, e0.y);
        d[1] = pk2i(e1.x, e1.y);
        d[2] = pk2i(e2.x, e2.y);
        d[3] = pk2i(e3.x, e3.y);
        d[4] = pk2i(e4.x, e4.y);
    }

    // ---- row assignment: wave w, lanes 0..59 own row w*60+lane (balanced) ----
    const bool hasrow = (lane < 60);
    const int  m      = min(wid * 60 + min(lane, 59), 299);   // clamped: all lanes load valid
    const int  g      = m / 100;
    const int  u      = m - g * 100;

    // ---- weights in NAMED vector registers (forces promotion) ----
    vi16 wA, wB, wC;          // whh packed half2: dwords 0..15, 16..31, 32..47
    int  wD0, wD1;            // dwords 48, 49
    int  wi0, wi1, wi2, wi3, wi4;
    float bih, bhh;
    {
        const float4* wr = (const float4*)(w_hh + m * MID);   // 400B rows: 16B aligned
        #pragma unroll
        for (int k = 0; k < 25; k++) {
            float4 f = wr[k];
            int lo = pk2i(f.x, f.y);
            int hi = pk2i(f.z, f.w);
            const int a = 2 * k, b = 2 * k + 1;
            if      (a < 16) wA[a] = lo;
            else if (a < 32) wB[a - 16] = lo;
            else if (a < 48) wC[a - 32] = lo;
            else             wD0 = lo;
            if      (b < 16) wA[b] = lo, wA[b] = hi;   // b<16 only when a<16
            else if (b < 32) wB[b - 16] = hi;
            else if (b < 48) wC[b - 32] = hi;
            else             wD1 = hi;
        }
        const float2* wi = (const float2*)(w_ih + m * 10);
        float2 f0 = wi[0], f1 = wi[1], f2 = wi[2], f3 = wi[3], f4 = wi[4];
        wi0 = pk2i(f0.x, f0.y);
        wi1 = pk2i(f1.x, f1.y);
        wi2 = pk2i(f2.x, f2.y);
        wi3 = pk2i(f3.x, f3.y);
        wi4 = pk2i(f4.x, f4.y);
        bih = b_ih[m];
        bhh = b_hh[m];
    }

    // ---- h state: EVERY wave keeps a full copy; lane l<50 owns units 2l,2l+1 ----
    const bool ownh = (lane < 50);
    float h0 = 0.0f, h1 = 0.0f;
    int   hpk = 0;
    if (ownh) {
        h0 = hidden[2 * lane];
        h1 = hidden[2 * lane + 1];
        hpk = pk2i(h0, h1);
    }

    __syncthreads();   // emb staging visible

    #pragma unroll 1
    for (int t = 0; t < SEQ; t++) {
        float* gb = &gates[t & 1][0][0];

        // ---- emb_t broadcast (same-address LDS reads) ----
        const int* eb = (const int*)&seq16[t * 16];
        int4 e4 = *(const int4*)eb;
        int  ew = eb[4];

        // ---- hh-matvec: h broadcast via intra-wave readlane (register-only) ----
        float a0 = bhh, a1 = 0.0f, a2 = 0.0f, a3 = 0.0f;
        #pragma unroll
        for (int k = 0; k < 48; k += 4) {
            int hk0 = __builtin_amdgcn_readlane(hpk, k);
            int hk1 = __builtin_amdgcn_readlane(hpk, k + 1);
            int hk2 = __builtin_amdgcn_readlane(hpk, k + 2);
            int hk3 = __builtin_amdgcn_readlane(hpk, k + 3);
            a0 = fdot2(i2h(WELT(k)),     i2h(hk0), a0);
            a1 = fdot2(i2h(WELT(k + 1)), i2h(hk1), a1);
            a2 = fdot2(i2h(WELT(k + 2)), i2h(hk2), a2);
            a3 = fdot2(i2h(WELT(k + 3)), i2h(hk3), a3);
        }
        {
            int hk0 = __builtin_amdgcn_readlane(hpk, 48);
            int hk1 = __builtin_amdgcn_readlane(hpk, 49);
            a0 = fdot2(i2h(wD0), i2h(hk0), a0);
            a1 = fdot2(i2h(wD1), i2h(hk1), a1);
        }
        float gh = (a0 + a1) + (a2 + a3);

        float gi = bih;
        gi = fdot2(i2h(wi0), i2h(e4.x), gi);
        gi = fdot2(i2h(wi1), i2h(e4.y), gi);
        gi = fdot2(i2h(wi2), i2h(e4.z), gi);
        gi = fdot2(i2h(wi3), i2h(e4.w), gi);
        gi = fdot2(i2h(wi4), i2h(ew),   gi);

        if (hasrow) {
            if (g == 2) { gb[2 * GST + u] = gi; gb[3 * GST + u] = gh; }
            else        { gb[g * GST + u] = gi + gh; }
        }
        __syncthreads();   // the ONLY barrier per step (gates double-buffered)

        // ---- phase 2: every wave redundantly updates all 100 units ----
        if (ownh) {
            float2 grv = *(const float2*)&gb[0 * GST + 2 * lane];
            float2 gzv = *(const float2*)&gb[1 * GST + 2 * lane];
            float2 giv = *(const float2*)&gb[2 * GST + 2 * lane];
            float2 ghv = *(const float2*)&gb[3 * GST + 2 * lane];
            float r0 = sigm(grv.x), z0 = sigm(gzv.x);
            float n0 = tanh_f(giv.x + r0 * ghv.x);
            h0 = n0 + z0 * (h0 - n0);
            float r1 = sigm(grv.y), z1 = sigm(gzv.y);
            float n1 = tanh_f(giv.y + r1 * ghv.y);
            h1 = n1 + z1 * (h1 - n1);
            hpk = pk2i(h0, h1);
        }
    }

    // ---- epilogue: sigmoid(relu(h) . fc_w + fc_b), wave 0's copy ----
    if (tid < 50)
        partial[tid] = fmaxf(h0, 0.0f) * fc_w[2 * tid]
                     + fmaxf(h1, 0.0f) * fc_w[2 * tid + 1];
    __syncthreads();
    if (tid == 0) {
        float s = fc_b[0];
        #pragma unroll 1
        for (int k = 0; k < 50; k++) s += partial[k];
        out[0] = sigm(s);
    }
}

extern "C" void kernel_launch(void* const* d_in, const int* in_sizes, int n_in,
                              void* d_out, int out_size, void* d_ws, size_t ws_size,
                              hipStream_t stream) {
    const int*   x      = (const int*)  d_in[0];
    const float* hidden = (const float*)d_in[1];
    const float* embed  = (const float*)d_in[2];
    const float* w_ih   = (const float*)d_in[3];
    const float* w_hh   = (const float*)d_in[4];
    const float* b_ih   = (const float*)d_in[5];
    const float* b_hh   = (const float*)d_in[6];
    const float* fc_w   = (const float*)d_in[7];
    const float* fc_b   = (const float*)d_in[8];
    float*       out    = (float*)d_out;

    gru6<<<1, TPB, 0, stream>>>(x, hidden, embed, w_ih, w_hh,
                                b_ih, b_hh, fc_w, fc_b, out);
}